// Round 4
// baseline (493.495 us; speedup 1.0000x reference)
//
#include <hip/hip_runtime.h>
#include <cmath>

#define MP1 524288
#define NXP 32768

typedef float v2f __attribute__((ext_vector_type(2)));

__device__ __forceinline__ float tanh_fast(float x) {
    // tanh(x) = 1 - 2/(exp(2x)+1); exact at +/-inf, ~1e-6 abs error.
    float e = __expf(2.0f * x);
    return fmaf(-2.0f, __builtin_amdgcn_rcpf(e + 1.0f), 1.0f);
}

// ws layout (float offsets):
//   [0,128)              b_acc (zeroed by prep1; ws is poisoned each launch)
//   [128,256)            cvec = Wt3^T (b_acc+bb)
//   [256]                u_const = dot(b, bt3)
//   [512, 512+16384)     WT2t[k*128+j] = Wt2[j*128+k]
//   [16896, 16896+4096)  WE2t[i*64+m]  = We2[m*64+i]

__global__ __launch_bounds__(256) void prep1_k(const float* __restrict__ Wt2,
                                               const float* __restrict__ We2,
                                               float* __restrict__ ws) {
    int idx = blockIdx.x * 256 + threadIdx.x;
    if (idx < 128) ws[idx] = 0.0f;
    if (idx < 16384) {
        int j = idx >> 7, k = idx & 127;
        ws[512 + k * 128 + j] = Wt2[idx];
    }
    if (idx < 4096) {
        int m = idx >> 6, i = idx & 63;
        ws[16896 + i * 64 + m] = We2[idx];
    }
}

__global__ __launch_bounds__(256) void gemv_k(const float* __restrict__ Wb,
                                              const float* __restrict__ a,
                                              float* __restrict__ b_acc) {
    const int row = blockIdx.y;
    const int chunk = blockIdx.x;
    const int t = threadIdx.x;
    size_t base = (size_t)row * MP1 + (size_t)chunk * 16384;
    const float4* W4 = (const float4*)(Wb + base);
    const float4* A4 = (const float4*)(a + (size_t)chunk * 16384);
    float sum = 0.0f;
#pragma unroll
    for (int it = 0; it < 16; ++it) {
        float4 w = W4[t + it * 256];
        float4 av = A4[t + it * 256];
        sum += w.x * av.x + w.y * av.y + w.z * av.z + w.w * av.w;
    }
#pragma unroll
    for (int off = 32; off > 0; off >>= 1) sum += __shfl_down(sum, off, 64);
    __shared__ float red[4];
    int wid = t >> 6;
    if ((t & 63) == 0) red[wid] = sum;
    __syncthreads();
    if (t == 0) atomicAdd(&b_acc[row], red[0] + red[1] + red[2] + red[3]);
}

__global__ __launch_bounds__(128) void prep2_k(const float* __restrict__ ws_in,
                                               const float* __restrict__ bb,
                                               const float* __restrict__ Wt3,
                                               const float* __restrict__ bt3,
                                               float* __restrict__ ws) {
    int k = threadIdx.x;
    float cv = 0.0f;
    for (int j = 0; j < 128; ++j)
        cv = fmaf(ws_in[j] + bb[j], Wt3[j * 128 + k], cv);
    ws[128 + k] = cv;
    float p = (ws_in[k] + bb[k]) * bt3[k];
#pragma unroll
    for (int off = 32; off > 0; off >>= 1) p += __shfl_down(p, off, 64);
    __shared__ float red[2];
    if ((k & 63) == 0) red[k >> 6] = p;
    __syncthreads();
    if (k == 0) ws[256] = red[0] + red[1];
}

// 512 threads = 8 wave-aligned slices x 64 points. Slice s owns trunk outputs
// j in [16s,16s+16) and energy outputs m in [8s,8s+8). lane = point. slice is
// provably uniform (readfirstlane) -> weight rows stay s_load. Jet GEMM
// streams are paired across adjacent output columns so the multiplier pair
// {w[2c],w[2c+1]} is an SGPR pair and the FMA lowers to v_pk_fma_f32
// (full-rate packed fp32) -> half the VALU issue slots.
#define H1V 0          // 8192 floats: trunk layer-1 tanh [k*64+p]; h1e aliases [0,4096) later
#define RED 8192       // 2048 floats: per-slice u partials [(s*64+p)*4+r]
#define URED 10240     // 256 floats:  reduced u jets [p*4+r]
#define FRED 10496     // 3072 floats: per-slice F partials [(s*64+p)*6+q]
#define LDSF 13568

__global__ __launch_bounds__(512, 4) void point_k(const float* __restrict__ x,
                                                  const float* __restrict__ tptr,
                                                  const float* __restrict__ Wt1,
                                                  const float* __restrict__ bt1,
                                                  const float* __restrict__ bt2,
                                                  const float* __restrict__ We1,
                                                  const float* __restrict__ be1,
                                                  const float* __restrict__ be2,
                                                  const float* __restrict__ We3,
                                                  const float* __restrict__ ws,
                                                  float* __restrict__ out) {
    __shared__ float lds[LDSF];
    const int tid = threadIdx.x;
    const int p = tid & 63;
    const int slice = __builtin_amdgcn_readfirstlane(tid >> 6);
    const int i = blockIdx.x * 64 + p;
    const float xi = x[i];
    const float tt = tptr[0];
    const float* __restrict__ cvec = ws + 128;
    const float* __restrict__ WT2t = ws + 512;
    const float* __restrict__ WE2t = ws + 16896;
    const float u_const = ws[256];

    // ---- Phase A: trunk layer-1 tanh values (16 k's per thread) ----
#pragma unroll
    for (int q = 0; q < 16; ++q) {
        int k = slice * 16 + q;
        float z = fmaf(Wt1[2 * k], xi, fmaf(Wt1[2 * k + 1], tt, bt1[k]));
        lds[H1V + k * 64 + p] = tanh_fast(z);
    }
    __syncthreads();

    // ---- Phase B: trunk layer-2 jets, this slice's 16 j's (packed fp32) ----
    {
        v2f A0[8], A1[8], A2[8], A3[8];
#pragma unroll
        for (int h = 0; h < 8; ++h) {
            A0[h] = (v2f)0.f; A1[h] = (v2f)0.f; A2[h] = (v2f)0.f; A3[h] = (v2f)0.f;
        }
#pragma unroll 2
        for (int k = 0; k < 128; ++k) {
            float v = lds[H1V + k * 64 + p];
            float w = Wt1[2 * k];            // uniform -> s_load
            float s = 1.f - v * v;
            float f2 = -2.f * v * s;
            float f3 = 2.f * s * (2.f * v * v - s);
            float d1 = s * w;
            float d2 = f2 * (w * w);
            float d3 = f3 * (w * w * w);
            v2f vv = {v, v}, dd1 = {d1, d1}, dd2 = {d2, d2}, dd3 = {d3, d3};
            const v2f* wrow = (const v2f*)(WT2t + k * 128 + slice * 16);  // uniform
#pragma unroll
            for (int h = 0; h < 8; ++h) {
                v2f wp = wrow[h];
                A0[h] = __builtin_elementwise_fma(wp, vv,  A0[h]);
                A1[h] = __builtin_elementwise_fma(wp, dd1, A1[h]);
                A2[h] = __builtin_elementwise_fma(wp, dd2, A2[h]);
                A3[h] = __builtin_elementwise_fma(wp, dd3, A3[h]);
            }
        }
        float u0 = 0.f, u1 = 0.f, u2 = 0.f, u3 = 0.f;
#pragma unroll
        for (int jj = 0; jj < 16; ++jj) {
            int j = slice * 16 + jj;         // uniform
            float z0 = A0[jj >> 1][jj & 1] + bt2[j];
            float z1 = A1[jj >> 1][jj & 1];
            float z2 = A2[jj >> 1][jj & 1];
            float z3 = A3[jj >> 1][jj & 1];
            float v = tanh_fast(z0);
            float s = 1.f - v * v;
            float f2 = -2.f * v * s;
            float f3 = 2.f * s * (2.f * v * v - s);
            float cj = cvec[j];
            u0 = fmaf(cj, v, u0);
            u1 = fmaf(cj, s * z1, u1);
            u2 = fmaf(cj, f2 * z1 * z1 + s * z2, u2);
            u3 = fmaf(cj, f3 * z1 * z1 * z1 + 3.f * f2 * z1 * z2 + s * z3, u3);
        }
        float* r = lds + RED + (slice * 64 + p) * 4;
        r[0] = u0; r[1] = u1; r[2] = u2; r[3] = u3;
    }
    __syncthreads();

    // ---- reduce u jets across slices (threads 0..63) ----
    if (tid < 64) {
        float u0 = u_const, u1 = 0.f, u2 = 0.f, u3 = 0.f;
#pragma unroll
        for (int s = 0; s < 8; ++s) {
            const float* r = lds + RED + (s * 64 + tid) * 4;
            u0 += r[0]; u1 += r[1]; u2 += r[2]; u3 += r[3];
        }
        float* u = lds + URED + tid * 4;
        u[0] = u0; u[1] = u1; u[2] = u2; u[3] = u3;
    }
    __syncthreads();

    const float y = lds[URED + p * 4 + 0];
    const float z = lds[URED + p * 4 + 1];

    // ---- Phase C part 1: energy layer-1 tanh values (8 ii's per thread) ----
#pragma unroll
    for (int q = 0; q < 8; ++q) {
        int ii = slice * 8 + q;
        float g = fmaf(We1[2 * ii], y, fmaf(We1[2 * ii + 1], z, be1[ii]));
        lds[H1V + ii * 64 + p] = tanh_fast(g);
    }
    __syncthreads();

    // ---- Phase C part 2: energy layer-2 jets, this slice's 8 m's (packed) ----
    {
        v2f B0[4], B1[4], B2[4], B3[4], B4[4], B5[4], B6[4], B7[4], B8[4];
#pragma unroll
        for (int h = 0; h < 4; ++h) {
            B0[h] = (v2f)0.f; B1[h] = (v2f)0.f; B2[h] = (v2f)0.f;
            B3[h] = (v2f)0.f; B4[h] = (v2f)0.f; B5[h] = (v2f)0.f;
            B6[h] = (v2f)0.f; B7[h] = (v2f)0.f; B8[h] = (v2f)0.f;
        }
#pragma unroll 2
        for (int ii = 0; ii < 64; ++ii) {
            float v = lds[H1V + ii * 64 + p];
            float w0 = We1[2 * ii], w1 = We1[2 * ii + 1];  // uniform -> s_load
            float s = 1.f - v * v;
            float f2 = -2.f * v * s;
            float f3 = 2.f * s * (2.f * v * v - s);
            float j1 = s * w0, j2 = s * w1;
            float j3 = f2 * (w0 * w0), j4 = f2 * (w0 * w1), j5 = f2 * (w1 * w1);
            float j6 = f3 * (w0 * w0 * w1), j7 = f3 * (w0 * w1 * w1), j8 = f3 * (w1 * w1 * w1);
            v2f sv = {v, v}, s1 = {j1, j1}, s2 = {j2, j2}, s3 = {j3, j3}, s4 = {j4, j4},
                s5 = {j5, j5}, s6 = {j6, j6}, s7 = {j7, j7}, s8 = {j8, j8};
            const v2f* wrow = (const v2f*)(WE2t + ii * 64 + slice * 8);  // uniform
#pragma unroll
            for (int h = 0; h < 4; ++h) {
                v2f wp = wrow[h];
                B0[h] = __builtin_elementwise_fma(wp, sv, B0[h]);
                B1[h] = __builtin_elementwise_fma(wp, s1, B1[h]);
                B2[h] = __builtin_elementwise_fma(wp, s2, B2[h]);
                B3[h] = __builtin_elementwise_fma(wp, s3, B3[h]);
                B4[h] = __builtin_elementwise_fma(wp, s4, B4[h]);
                B5[h] = __builtin_elementwise_fma(wp, s5, B5[h]);
                B6[h] = __builtin_elementwise_fma(wp, s6, B6[h]);
                B7[h] = __builtin_elementwise_fma(wp, s7, B7[h]);
                B8[h] = __builtin_elementwise_fma(wp, s8, B8[h]);
            }
        }
        float Fyy = 0.f, Fyz = 0.f, Fzz = 0.f, Fyyz = 0.f, Fyzz = 0.f, Fzzz = 0.f;
#pragma unroll
        for (int mm = 0; mm < 8; ++mm) {
            int m = slice * 8 + mm;          // uniform
            int h = mm >> 1, e = mm & 1;
            float G0 = B0[h][e] + be2[m];
            float v = tanh_fast(G0);
            float s = 1.f - v * v;
            float f2 = -2.f * v * s;
            float f3 = 2.f * s * (2.f * v * v - s);
            float Gy = B1[h][e], Gz = B2[h][e];
            float Gyy = B3[h][e], Gyz = B4[h][e], Gzz = B5[h][e];
            float Hyy = f2 * Gy * Gy + s * Gyy;
            float Hyz = f2 * Gy * Gz + s * Gyz;
            float Hzz = f2 * Gz * Gz + s * Gzz;
            float Hyyz = f3 * Gy * Gy * Gz + f2 * (Gyy * Gz + 2.f * Gyz * Gy) + s * B6[h][e];
            float Hyzz = f3 * Gy * Gz * Gz + f2 * (2.f * Gyz * Gz + Gzz * Gy) + s * B7[h][e];
            float Hzzz = f3 * Gz * Gz * Gz + 3.f * f2 * Gzz * Gz + s * B8[h][e];
            float w3 = We3[m];
            Fyy  = fmaf(w3, Hyy,  Fyy);
            Fyz  = fmaf(w3, Hyz,  Fyz);
            Fzz  = fmaf(w3, Hzz,  Fzz);
            Fyyz = fmaf(w3, Hyyz, Fyyz);
            Fyzz = fmaf(w3, Hyzz, Fyzz);
            Fzzz = fmaf(w3, Hzzz, Fzzz);
        }
        float* r = lds + FRED + (slice * 64 + p) * 6;
        r[0] = Fyy; r[1] = Fyz; r[2] = Fzz; r[3] = Fyyz; r[4] = Fyzz; r[5] = Fzzz;
    }
    __syncthreads();

    // ---- reduce F partials + combine (threads 0..63) ----
    if (tid < 64) {
        float F[6] = {0.f, 0.f, 0.f, 0.f, 0.f, 0.f};
#pragma unroll
        for (int s = 0; s < 8; ++s) {
            const float* r = lds + FRED + (s * 64 + tid) * 6;
#pragma unroll
            for (int q = 0; q < 6; ++q) F[q] += r[q];
        }
        const float* u = lds + URED + tid * 4;
        float u1 = u[1], u2 = u[2], u3 = u[3];
        float F_yx  = F[0] * u1 + F[1] * u2;
        float F_zxx = F[1] * u2 + F[2] * u3 + F[3] * u1 * u1
                    + 2.f * F[4] * u1 * u2 + F[5] * u2 * u2;
        out[blockIdx.x * 64 + tid] = F_zxx - F_yx;
    }
}

extern "C" void kernel_launch(void* const* d_in, const int* in_sizes, int n_in,
                              void* d_out, int out_size, void* d_ws, size_t ws_size,
                              hipStream_t stream) {
    const float* a   = (const float*)d_in[0];
    const float* x   = (const float*)d_in[1];
    const float* t   = (const float*)d_in[2];
    const float* Wb  = (const float*)d_in[3];
    const float* bb  = (const float*)d_in[4];
    const float* Wt1 = (const float*)d_in[5];
    const float* bt1 = (const float*)d_in[6];
    const float* Wt2 = (const float*)d_in[7];
    const float* bt2 = (const float*)d_in[8];
    const float* Wt3 = (const float*)d_in[9];
    const float* bt3 = (const float*)d_in[10];
    const float* We1 = (const float*)d_in[11];
    const float* be1 = (const float*)d_in[12];
    const float* We2 = (const float*)d_in[13];
    const float* be2 = (const float*)d_in[14];
    const float* We3 = (const float*)d_in[15];

    float* ws = (float*)d_ws;
    float* out = (float*)d_out;

    prep1_k<<<64, 256, 0, stream>>>(Wt2, We2, ws);
    gemv_k<<<dim3(32, 128), 256, 0, stream>>>(Wb, a, ws);
    prep2_k<<<1, 128, 0, stream>>>(ws, bb, Wt3, bt3, ws);
    point_k<<<NXP / 64, 512, 0, stream>>>(x, t, Wt1, bt1, bt2, We1, be1, be2, We3,
                                          ws, out);
}